// Round 15
// baseline (344.420 us; speedup 1.0000x reference)
//
#include <hip/hip_runtime.h>
#include <hip/hip_bf16.h>
#include <math.h>

#define NN 512   // hidden states
#define MM 256   // timesteps / emission symbols
#define BB 128   // batch

typedef float        f32x4 __attribute__((ext_vector_type(4)));
typedef unsigned int u32;
typedef u32          u32x2 __attribute__((ext_vector_type(2)));
typedef unsigned long long u64;
typedef int          i32x8 __attribute__((ext_vector_type(8)));

#define LOG16F 2.772588722239781f
#define SCL1   0x7F   // E8M0 scale byte = 1.0

__device__ __forceinline__ float wave_max(float v) {
#pragma unroll
    for (int o = 32; o > 0; o >>= 1) v = fmaxf(v, __shfl_xor(v, o));
    return v;
}
__device__ __forceinline__ float wave_sum(float v) {
#pragma unroll
    for (int o = 32; o > 0; o >>= 1) v += __shfl_xor(v, o);
    return v;
}

// ---------------- preprocessing (3 kernels) ----------------

// Column k logsumexp of T. grid 512 x 64 (one block per column).
__global__ void k_col_lse(const float* __restrict__ T, float* __restrict__ c) {
    int k = blockIdx.x, j = threadIdx.x;
    float m = -INFINITY, s = 0.f;
#pragma unroll
    for (int q = 0; q < 8; ++q) {
        float x = T[(q * 64 + j) * NN + k];
        if (x > m) { s = s * __expf(m - x) + 1.f; m = x; }
        else       { s += __expf(x - m); }
    }
    float mw = wave_max(m);
    float sw = wave_sum(s * __expf(m - mw));
    if (j == 0) c[k] = mw + __logf(sw);
}

// Row max: M[i] = max_k(T[i,k]-c[k]) - log(64). grid 512 x 64.
__global__ void k_rowM(const float* __restrict__ T, const float* __restrict__ c,
                       float* __restrict__ M) {
    int i = blockIdx.x, j = threadIdx.x;
    float mx = -INFINITY;
#pragma unroll
    for (int d = 0; d < 8; ++d) {
        int k = j * 8 + d;
        mx = fmaxf(mx, T[i * NN + k] - c[k]);
    }
    mx = wave_max(mx);
    if (j == 0) M[i] = mx - __logf(64.f);
}

// Fused prep: blocks 0..511 -> rowEX(i=blk); 512..639 -> packA(blk-512);
// 640 -> priors. C_M recomputed redundantly per block from M (8 loads+reduce).
__global__ void k_prep(const float* __restrict__ T, const float* __restrict__ c,
                       const float* __restrict__ M, const float* __restrict__ pr,
                       const float* __restrict__ E,
                       float* __restrict__ lp2, u32* __restrict__ PA,
                       float* __restrict__ EX) {
    int blk = blockIdx.x, l = threadIdx.x;
    if (blk < 512) {
        // ---- rowEX for row i = blk ----
        float mm = -INFINITY;
#pragma unroll
        for (int q = 0; q < 8; ++q) mm = fmaxf(mm, M[q * 64 + l]);
        float CMv = wave_max(mm);
        int i = blk;
        float v[4];
        float mx = -INFINITY;
#pragma unroll
        for (int d = 0; d < 4; ++d) {
            v[d] = E[i * MM + l * 4 + d];
            mx = fmaxf(mx, v[d]);
        }
        mx = wave_max(mx);
        float s = 0.f;
#pragma unroll
        for (int d = 0; d < 4; ++d) s += __expf(v[d] - mx);
        s = wave_sum(s);
        float lse = mx + __logf(s);
        float add = M[i] - CMv - LOG16F - lse;
#pragma unroll
        for (int d = 0; d < 4; ++d)
            EX[(size_t)(l * 4 + d) * NN + i] = __expf(v[d] + add);
    } else if (blk < 640) {
        // ---- packA: fp8 A-frags for mfma_scale 16x16x128, scaled x64 ----
        int bb = blk - 512;
        int tile = bb >> 2, kc = bb & 3;
        int row = tile * 16 + (l & 15);
        int kb  = kc * 128 + (l >> 4) * 32;
        float Mi = M[row];                // = rowmax - log64
        i32x8 dd;
#pragma unroll
        for (int q = 0; q < 8; ++q) {
            float p0 = __expf(T[row * NN + kb + 4*q + 0] - c[kb + 4*q + 0] - Mi);
            float p1 = __expf(T[row * NN + kb + 4*q + 1] - c[kb + 4*q + 1] - Mi);
            float p2 = __expf(T[row * NN + kb + 4*q + 2] - c[kb + 4*q + 2] - Mi);
            float p3 = __expf(T[row * NN + kb + 4*q + 3] - c[kb + 4*q + 3] - Mi);
            int d = 0;
            d = __builtin_amdgcn_cvt_pk_fp8_f32(p0, p1, d, false);
            d = __builtin_amdgcn_cvt_pk_fp8_f32(p2, p3, d, true);
            dd[q] = d;
        }
        *(i32x8*)(PA + ((size_t)bb * 64 + l) * 8) = dd;
    } else {
        // ---- priors: lp2[i] = exp(log_softmax(pr)[i] - M[i] + C_M + log16) ----
        float mm = -INFINITY;
#pragma unroll
        for (int q = 0; q < 8; ++q) mm = fmaxf(mm, M[q * 64 + l]);
        float CMv = wave_max(mm);
        float x[8];
        float mx = -INFINITY;
#pragma unroll
        for (int q = 0; q < 8; ++q) {
            x[q] = pr[q * 64 + l];
            mx = fmaxf(mx, x[q]);
        }
        mx = wave_max(mx);
        float s = 0.f;
#pragma unroll
        for (int q = 0; q < 8; ++q) s += __expf(x[q] - mx);
        s = wave_sum(s);
        float lse = mx + __logf(s);
#pragma unroll
        for (int q = 0; q < 8; ++q) {
            int i = q * 64 + l;
            lp2[i] = __expf(x[q] - lse - M[i] + CMv + LOG16F);
        }
    }
}

// ---------------- the scan (MX K=128 MFMA, barrier-drain-aware) ----------------
// One block per batch, 512 threads = 8 waves. Wave w owns i-tiles w*4..w*4+3.
// 16 mfma_scale_f32_16x16x128_f8f6f4 per wave per step (scales = 1.0 exact),
// A-frags AGPR-resident, u-hat fp8 LINEAR in LDS. Fresh scale 16/S_t.
// Barrier-drain discipline: EX loads issued at step TOP (complete under MFMA,
// nothing in flight at B1); per-step outputs buffered in LDS and flushed to
// global ONCE at the end (no global store in flight at any barrier).
__global__ __launch_bounds__(512, 2) void k_scan(
        const int* __restrict__ obs, const float* __restrict__ lp2,
        const float* __restrict__ Mrow, const u32* __restrict__ PAu,
        const float* __restrict__ EX, float* __restrict__ out) {
    int b = blockIdx.x, tid = threadIdx.x;
    int w = tid >> 6, l = tid & 63;
    int h32 = (l >> 4) * 32;              // byte offset of this lane's B slice
    int r4 = (l >> 4) * 4;                // row group within a 16-row tile
    __shared__ unsigned char us8[NN] __attribute__((aligned(64)));
    __shared__ float rB[8] __attribute__((aligned(16)));
    __shared__ float outs[MM] __attribute__((aligned(16)));
    __shared__ int obs_s[MM];
    if (tid < MM) obs_s[tid] = obs[b * MM + tid];

    // C_M redundant compute (8 loads + wave reduce)
    float mm = -INFINITY;
#pragma unroll
    for (int q = 0; q < 8; ++q) mm = fmaxf(mm, Mrow[q * 64 + l]);
    float C_M = wave_max(mm);

    // --- stage A-fragments: 16 x i32x8 per lane (4 tiles x 4 k-chunks) ---
    i32x8 pa[16];
#pragma unroll
    for (int ti = 0; ti < 4; ++ti)
#pragma unroll
        for (int kc = 0; kc < 4; ++kc)
            pa[ti * 4 + kc] = *(const i32x8*)(PAu
                + ((size_t)(((w * 4 + ti) * 4 + kc) * 64) + l) * 8);
#pragma unroll
    for (int q = 0; q < 16; ++q) asm volatile("" : "+a"(pa[q]));  // AGPR-resident

    int ubase[4];
#pragma unroll
    for (int ti = 0; ti < 4; ++ti) ubase[ti] = (w * 4 + ti) * 16 + r4;
    __syncthreads();                      // obs_s ready

    // ---- t = 0: e = EX[o0] * lp2 ----
    int o0 = obs_s[0];
    f32x4 e4[4];
    float loc = 0.f;
#pragma unroll
    for (int ti = 0; ti < 4; ++ti) {
        f32x4 ex  = *(const f32x4*)(EX  + (size_t)o0 * NN + (w * 4 + ti) * 16 + r4);
        f32x4 lpv = *(const f32x4*)(lp2 + (w * 4 + ti) * 16 + r4);
#pragma unroll
        for (int r = 0; r < 4; ++r) {
            float e = ex[r] * lpv[r];
            e4[ti][r] = e; loc += e;
        }
    }
    loc += __shfl_xor(loc, 16);
    loc += __shfl_xor(loc, 32);
    if (l == 0) rB[w] = loc;
    __syncthreads();                      // B1
    f32x4 sv0 = *(const f32x4*)rB;
    f32x4 sv1 = *(const f32x4*)(rB + 4);
    float S = (sv0[0] + sv0[1]) + (sv0[2] + sv0[3])
            + (sv1[0] + sv1[1]) + (sv1[2] + sv1[3]);
    S = fmaxf(S, 1e-35f);
    float sc = __builtin_amdgcn_rcpf(S) * 16.f;
    if ((l & 15) == 0) {
#pragma unroll
        for (int ti = 0; ti < 4; ++ti) {
            int d = 0;
            d = __builtin_amdgcn_cvt_pk_fp8_f32(e4[ti][0] * sc, e4[ti][1] * sc, d, false);
            d = __builtin_amdgcn_cvt_pk_fp8_f32(e4[ti][2] * sc, e4[ti][3] * sc, d, true);
            *(u32*)&us8[ubase[ti]] = (u32)d;
        }
    }
    __syncthreads();                      // B2: us8 ready
    float lS = __logf(S);
    if (tid == 0) outs[0] = lS;
    float K = C_M + lS;                   // Omega_1

    // ---- main scan t >= 1 ----
#pragma unroll 1
    for (int t = 1; t < MM; ++t) {
        // issue this step's EX loads FIRST: latency hides under the MFMA
        // block and they are COMPLETE by B1 (no vmcnt drain stall).
        int o = obs_s[t];
        f32x4 ex[4];
#pragma unroll
        for (int ti = 0; ti < 4; ++ti)
            ex[ti] = *(const f32x4*)(EX + (size_t)o * NN + (w * 4 + ti) * 16 + r4);

        const unsigned char* ub = us8;
        f32x4 a0 = {0.f,0.f,0.f,0.f}, a1 = {0.f,0.f,0.f,0.f};
        f32x4 a2 = {0.f,0.f,0.f,0.f}, a3 = {0.f,0.f,0.f,0.f};
        f32x4 b0 = {0.f,0.f,0.f,0.f}, b1 = {0.f,0.f,0.f,0.f};
        f32x4 b2 = {0.f,0.f,0.f,0.f}, b3 = {0.f,0.f,0.f,0.f};
        __builtin_amdgcn_s_setprio(1);
#pragma unroll
        for (int kc = 0; kc < 2; ++kc) {   // chains of depth 2 (8 accumulators)
            i32x8 bbA = *(const i32x8*)(ub + kc * 128 + h32);
            i32x8 bbB = *(const i32x8*)(ub + (kc + 2) * 128 + h32);
            a0 = __builtin_amdgcn_mfma_scale_f32_16x16x128_f8f6f4(
                     pa[0 * 4 + kc], bbA, a0, 0, 0, 0, SCL1, 0, SCL1);
            a1 = __builtin_amdgcn_mfma_scale_f32_16x16x128_f8f6f4(
                     pa[1 * 4 + kc], bbA, a1, 0, 0, 0, SCL1, 0, SCL1);
            a2 = __builtin_amdgcn_mfma_scale_f32_16x16x128_f8f6f4(
                     pa[2 * 4 + kc], bbA, a2, 0, 0, 0, SCL1, 0, SCL1);
            a3 = __builtin_amdgcn_mfma_scale_f32_16x16x128_f8f6f4(
                     pa[3 * 4 + kc], bbA, a3, 0, 0, 0, SCL1, 0, SCL1);
            b0 = __builtin_amdgcn_mfma_scale_f32_16x16x128_f8f6f4(
                     pa[0 * 4 + kc + 2], bbB, b0, 0, 0, 0, SCL1, 0, SCL1);
            b1 = __builtin_amdgcn_mfma_scale_f32_16x16x128_f8f6f4(
                     pa[1 * 4 + kc + 2], bbB, b1, 0, 0, 0, SCL1, 0, SCL1);
            b2 = __builtin_amdgcn_mfma_scale_f32_16x16x128_f8f6f4(
                     pa[2 * 4 + kc + 2], bbB, b2, 0, 0, 0, SCL1, 0, SCL1);
            b3 = __builtin_amdgcn_mfma_scale_f32_16x16x128_f8f6f4(
                     pa[3 * 4 + kc + 2], bbB, b3, 0, 0, 0, SCL1, 0, SCL1);
        }
        __builtin_amdgcn_s_setprio(0);
        f32x4 sacc[4] = { a0 + b0, a1 + b1, a2 + b2, a3 + b3 };

        // e = ex * s_raw (ex loads complete by now)
        loc = 0.f;
#pragma unroll
        for (int ti = 0; ti < 4; ++ti)
#pragma unroll
            for (int r = 0; r < 4; ++r) {
                float e = ex[ti][r] * sacc[ti][r];
                e4[ti][r] = e; loc += e;
            }
        loc += __shfl_xor(loc, 16);
        loc += __shfl_xor(loc, 32);
        if (l == 0) rB[w] = loc;
        __syncthreads();                  // B1: rB ready (us8 reads done too)
        sv0 = *(const f32x4*)rB;
        sv1 = *(const f32x4*)(rB + 4);
        S = (sv0[0] + sv0[1]) + (sv0[2] + sv0[3])
          + (sv1[0] + sv1[1]) + (sv1[2] + sv1[3]);
        S = fmaxf(S, 1e-35f);
        sc = __builtin_amdgcn_rcpf(S) * 16.f;
        if ((l & 15) == 0) {
#pragma unroll
            for (int ti = 0; ti < 4; ++ti) {
                int d = 0;
                d = __builtin_amdgcn_cvt_pk_fp8_f32(e4[ti][0] * sc, e4[ti][1] * sc, d, false);
                d = __builtin_amdgcn_cvt_pk_fp8_f32(e4[ti][2] * sc, e4[ti][3] * sc, d, true);
                *(u32*)&us8[ubase[ti]] = (u32)d;
            }
        }
        __syncthreads();                  // B2: us8 ready for next step
        // deferred bookkeeping: LDS write only (no global store in flight)
        float lSn = __logf(S);
        if (tid == 0) outs[t] = K + lSn;
        K += C_M + lSn;                   // Omega_{t+1}
    }

    // flush outputs once, coalesced
    __syncthreads();
    if (tid < MM) out[(size_t)b * MM + tid] = outs[tid];
}

extern "C" void kernel_launch(void* const* d_in, const int* in_sizes, int n_in,
                              void* d_out, int out_size, void* d_ws, size_t ws_size,
                              hipStream_t stream) {
    const int*   obs = (const int*)d_in[0];
    const float* pri = (const float*)d_in[1];
    const float* T   = (const float*)d_in[2];
    const float* E   = (const float*)d_in[3];
    float* out = (float*)d_out;
    char* ws = (char*)d_ws;

    float* c   = (float*)(ws + 0);
    float* lp2 = (float*)(ws + 2048);
    float* M   = (float*)(ws + 4096);
    u32*   PA  = (u32*)(ws + 8192);                       // 256 KB fp8 A-frags
    float* EX  = (float*)(ws + 8192 + 256 * 1024);        // 512 KB

    k_col_lse<<<512, 64, 0, stream>>>(T, c);
    k_rowM   <<<512, 64, 0, stream>>>(T, c, M);
    k_prep   <<<641, 64, 0, stream>>>(T, c, M, pri, E, lp2, PA, EX);
    k_scan   <<<BB, 512, 0, stream>>>(obs, lp2, M, PA, EX, out);
}

// Round 16
// 330.437 us; speedup vs baseline: 1.0423x; 1.0423x over previous
//
#include <hip/hip_runtime.h>
#include <hip/hip_bf16.h>
#include <math.h>

#define NN 512   // hidden states
#define MM 256   // timesteps / emission symbols
#define BB 128   // batch

typedef float        f32x4 __attribute__((ext_vector_type(4)));
typedef unsigned int u32;
typedef u32          u32x2 __attribute__((ext_vector_type(2)));
typedef unsigned long long u64;
typedef int          i32x8 __attribute__((ext_vector_type(8)));

#define LOG16F 2.772588722239781f
#define LN2F   0.6931471805599453f
#define SCL1   0x7F   // E8M0 scale byte = 1.0

__device__ __forceinline__ float wave_max(float v) {
#pragma unroll
    for (int o = 32; o > 0; o >>= 1) v = fmaxf(v, __shfl_xor(v, o));
    return v;
}
__device__ __forceinline__ float wave_sum(float v) {
#pragma unroll
    for (int o = 32; o > 0; o >>= 1) v += __shfl_xor(v, o);
    return v;
}
__device__ __forceinline__ int fexp(float x) {       // ilogb for positive x
    return ((__float_as_int(x) >> 23) & 255) - 127;
}

// ---------------- preprocessing (3 kernels, unchanged from r14) ----------------

__global__ void k_col_lse(const float* __restrict__ T, float* __restrict__ c) {
    int k = blockIdx.x, j = threadIdx.x;
    float m = -INFINITY, s = 0.f;
#pragma unroll
    for (int q = 0; q < 8; ++q) {
        float x = T[(q * 64 + j) * NN + k];
        if (x > m) { s = s * __expf(m - x) + 1.f; m = x; }
        else       { s += __expf(x - m); }
    }
    float mw = wave_max(m);
    float sw = wave_sum(s * __expf(m - mw));
    if (j == 0) c[k] = mw + __logf(sw);
}

__global__ void k_rowM(const float* __restrict__ T, const float* __restrict__ c,
                       float* __restrict__ M) {
    int i = blockIdx.x, j = threadIdx.x;
    float mx = -INFINITY;
#pragma unroll
    for (int d = 0; d < 8; ++d) {
        int k = j * 8 + d;
        mx = fmaxf(mx, T[i * NN + k] - c[k]);
    }
    mx = wave_max(mx);
    if (j == 0) M[i] = mx - __logf(64.f);
}

__global__ void k_prep(const float* __restrict__ T, const float* __restrict__ c,
                       const float* __restrict__ M, const float* __restrict__ pr,
                       const float* __restrict__ E,
                       float* __restrict__ lp2, u32* __restrict__ PA,
                       float* __restrict__ EX) {
    int blk = blockIdx.x, l = threadIdx.x;
    if (blk < 512) {
        float mm = -INFINITY;
#pragma unroll
        for (int q = 0; q < 8; ++q) mm = fmaxf(mm, M[q * 64 + l]);
        float CMv = wave_max(mm);
        int i = blk;
        float v[4];
        float mx = -INFINITY;
#pragma unroll
        for (int d = 0; d < 4; ++d) {
            v[d] = E[i * MM + l * 4 + d];
            mx = fmaxf(mx, v[d]);
        }
        mx = wave_max(mx);
        float s = 0.f;
#pragma unroll
        for (int d = 0; d < 4; ++d) s += __expf(v[d] - mx);
        s = wave_sum(s);
        float lse = mx + __logf(s);
        float add = M[i] - CMv - LOG16F - lse;
#pragma unroll
        for (int d = 0; d < 4; ++d)
            EX[(size_t)(l * 4 + d) * NN + i] = __expf(v[d] + add);
    } else if (blk < 640) {
        int bb = blk - 512;
        int tile = bb >> 2, kc = bb & 3;
        int row = tile * 16 + (l & 15);
        int kb  = kc * 128 + (l >> 4) * 32;
        float Mi = M[row];                // = rowmax - log64
        i32x8 dd;
#pragma unroll
        for (int q = 0; q < 8; ++q) {
            float p0 = __expf(T[row * NN + kb + 4*q + 0] - c[kb + 4*q + 0] - Mi);
            float p1 = __expf(T[row * NN + kb + 4*q + 1] - c[kb + 4*q + 1] - Mi);
            float p2 = __expf(T[row * NN + kb + 4*q + 2] - c[kb + 4*q + 2] - Mi);
            float p3 = __expf(T[row * NN + kb + 4*q + 3] - c[kb + 4*q + 3] - Mi);
            int d = 0;
            d = __builtin_amdgcn_cvt_pk_fp8_f32(p0, p1, d, false);
            d = __builtin_amdgcn_cvt_pk_fp8_f32(p2, p3, d, true);
            dd[q] = d;
        }
        *(i32x8*)(PA + ((size_t)bb * 64 + l) * 8) = dd;
    } else {
        float mm = -INFINITY;
#pragma unroll
        for (int q = 0; q < 8; ++q) mm = fmaxf(mm, M[q * 64 + l]);
        float CMv = wave_max(mm);
        float x[8];
        float mx = -INFINITY;
#pragma unroll
        for (int q = 0; q < 8; ++q) {
            x[q] = pr[q * 64 + l];
            mx = fmaxf(mx, x[q]);
        }
        mx = wave_max(mx);
        float s = 0.f;
#pragma unroll
        for (int q = 0; q < 8; ++q) s += __expf(x[q] - mx);
        s = wave_sum(s);
        float lse = mx + __logf(s);
#pragma unroll
        for (int q = 0; q < 8; ++q) {
            int i = q * 64 + l;
            lp2[i] = __expf(x[q] - lse - M[i] + CMv + LOG16F);
        }
    }
}

// ---------------- the scan (MX K=128, 1 barrier/step for t>=3) ----------------
// One block per batch, 512 threads = 8 waves. Wave w owns i-tiles w*4..w*4+3.
// Publish u-hat = e * 2^(6-W): W integer, damped update W += (x-W)>>1 from the
// PREVIOUS step's max exponent x (post-barrier, off critical path). Scale is a
// power of 2 recorded EXACTLY in Omega: K += C_M + log16 + (W-6)*ln2.
// No r8-style oscillation: x_{t+1} already reflects W_t (no double-compensation),
// and the update is half-damped. Steps 0..2 use the fresh r14 path (2 barriers)
// to kill the startup transient; W initialized from x_2.
__global__ __launch_bounds__(512, 2) void k_scan(
        const int* __restrict__ obs, const float* __restrict__ lp2,
        const float* __restrict__ Mrow, const u32* __restrict__ PAu,
        const float* __restrict__ EX, float* __restrict__ out) {
    int b = blockIdx.x, tid = threadIdx.x;
    int w = tid >> 6, l = tid & 63;
    int h32 = (l >> 4) * 32;              // byte offset of this lane's B slice
    int r4 = (l >> 4) * 4;                // row group within a 16-row tile
    __shared__ unsigned char us8[2][NN] __attribute__((aligned(64)));
    __shared__ float rB[2][8] __attribute__((aligned(16)));
    __shared__ int   rEm[2][8] __attribute__((aligned(16)));
    __shared__ int obs_s[MM];
    if (tid < MM) obs_s[tid] = obs[b * MM + tid];

    // C_M (8 loads + wave reduce)
    float mm = -INFINITY;
#pragma unroll
    for (int q = 0; q < 8; ++q) mm = fmaxf(mm, Mrow[q * 64 + l]);
    float C_M = wave_max(mm);

    // --- stage A-fragments: 16 x i32x8 per lane (4 tiles x 4 k-chunks) ---
    i32x8 pa[16];
#pragma unroll
    for (int ti = 0; ti < 4; ++ti)
#pragma unroll
        for (int kc = 0; kc < 4; ++kc)
            pa[ti * 4 + kc] = *(const i32x8*)(PAu
                + ((size_t)(((w * 4 + ti) * 4 + kc) * 64) + l) * 8);
#pragma unroll
    for (int q = 0; q < 16; ++q) asm volatile("" : "+a"(pa[q]));  // AGPR-resident

    int ubase[4];
#pragma unroll
    for (int ti = 0; ti < 4; ++ti) ubase[ti] = (w * 4 + ti) * 16 + r4;
    __syncthreads();                      // obs_s ready

    // ---- t = 0: e = EX[o0] * lp2, fresh publish ----
    int o0 = obs_s[0];
    f32x4 e4[4];
    float loc = 0.f;
#pragma unroll
    for (int ti = 0; ti < 4; ++ti) {
        f32x4 ex  = *(const f32x4*)(EX  + (size_t)o0 * NN + (w * 4 + ti) * 16 + r4);
        f32x4 lpv = *(const f32x4*)(lp2 + (w * 4 + ti) * 16 + r4);
#pragma unroll
        for (int r = 0; r < 4; ++r) {
            float e = ex[r] * lpv[r];
            e4[ti][r] = e; loc += e;
        }
    }
    loc += __shfl_xor(loc, 16);
    loc += __shfl_xor(loc, 32);
    if (l == 0) rB[0][w] = loc;
    __syncthreads();                      // B1
    f32x4 sv0 = *(const f32x4*)rB[0];
    f32x4 sv1 = *(const f32x4*)(rB[0] + 4);
    float S = (sv0[0] + sv0[1]) + (sv0[2] + sv0[3])
            + (sv1[0] + sv1[1]) + (sv1[2] + sv1[3]);
    S = fmaxf(S, 1e-35f);
    float sc = __builtin_amdgcn_rcpf(S) * 16.f;
    if ((l & 15) == 0) {
#pragma unroll
        for (int ti = 0; ti < 4; ++ti) {
            int d = 0;
            d = __builtin_amdgcn_cvt_pk_fp8_f32(e4[ti][0] * sc, e4[ti][1] * sc, d, false);
            d = __builtin_amdgcn_cvt_pk_fp8_f32(e4[ti][2] * sc, e4[ti][3] * sc, d, true);
            *(u32*)&us8[0][ubase[ti]] = (u32)d;
        }
    }
    __syncthreads();                      // B2: us8[0] ready
    float lS = __logf(S);
    if (tid == 0) out[(size_t)b * MM + 0] = lS;
    float K = C_M + lS;                   // Omega_1

    // prefetch t=1 emission row
    f32x4 exn[4];
    {
        int on = obs_s[1];
#pragma unroll
        for (int ti = 0; ti < 4; ++ti)
            exn[ti] = *(const f32x4*)(EX + (size_t)on * NN + (w * 4 + ti) * 16 + r4);
    }

    int W = 0;

    // ---- t = 1..2: fresh publish (2 barriers), track max exponent for W ----
#pragma unroll 1
    for (int t = 1; t <= 2; ++t) {
        int p = t & 1, pr = p ^ 1;
        const unsigned char* ub = us8[pr];
        f32x4 a0 = {0.f,0.f,0.f,0.f}, a1 = {0.f,0.f,0.f,0.f};
        f32x4 a2 = {0.f,0.f,0.f,0.f}, a3 = {0.f,0.f,0.f,0.f};
        f32x4 b0 = {0.f,0.f,0.f,0.f}, b1 = {0.f,0.f,0.f,0.f};
        f32x4 b2 = {0.f,0.f,0.f,0.f}, b3 = {0.f,0.f,0.f,0.f};
        __builtin_amdgcn_s_setprio(1);
#pragma unroll
        for (int kc = 0; kc < 2; ++kc) {
            i32x8 bbA = *(const i32x8*)(ub + kc * 128 + h32);
            i32x8 bbB = *(const i32x8*)(ub + (kc + 2) * 128 + h32);
            a0 = __builtin_amdgcn_mfma_scale_f32_16x16x128_f8f6f4(pa[0*4+kc],   bbA, a0, 0,0,0, SCL1, 0, SCL1);
            a1 = __builtin_amdgcn_mfma_scale_f32_16x16x128_f8f6f4(pa[1*4+kc],   bbA, a1, 0,0,0, SCL1, 0, SCL1);
            a2 = __builtin_amdgcn_mfma_scale_f32_16x16x128_f8f6f4(pa[2*4+kc],   bbA, a2, 0,0,0, SCL1, 0, SCL1);
            a3 = __builtin_amdgcn_mfma_scale_f32_16x16x128_f8f6f4(pa[3*4+kc],   bbA, a3, 0,0,0, SCL1, 0, SCL1);
            b0 = __builtin_amdgcn_mfma_scale_f32_16x16x128_f8f6f4(pa[0*4+kc+2], bbB, b0, 0,0,0, SCL1, 0, SCL1);
            b1 = __builtin_amdgcn_mfma_scale_f32_16x16x128_f8f6f4(pa[1*4+kc+2], bbB, b1, 0,0,0, SCL1, 0, SCL1);
            b2 = __builtin_amdgcn_mfma_scale_f32_16x16x128_f8f6f4(pa[2*4+kc+2], bbB, b2, 0,0,0, SCL1, 0, SCL1);
            b3 = __builtin_amdgcn_mfma_scale_f32_16x16x128_f8f6f4(pa[3*4+kc+2], bbB, b3, 0,0,0, SCL1, 0, SCL1);
        }
        __builtin_amdgcn_s_setprio(0);
        f32x4 sacc[4] = { a0 + b0, a1 + b1, a2 + b2, a3 + b3 };

        loc = 0.f;
        float lmax = 0.f;
#pragma unroll
        for (int ti = 0; ti < 4; ++ti)
#pragma unroll
            for (int r = 0; r < 4; ++r) {
                float e = exn[ti][r] * sacc[ti][r];
                e4[ti][r] = e; loc += e;
                lmax = fmaxf(lmax, e);
            }

        int on = obs_s[t + 1];
#pragma unroll
        for (int ti = 0; ti < 4; ++ti)
            exn[ti] = *(const f32x4*)(EX + (size_t)on * NN + (w * 4 + ti) * 16 + r4);

        loc += __shfl_xor(loc, 16);
        loc += __shfl_xor(loc, 32);
        lmax = fmaxf(lmax, __shfl_xor(lmax, 16));
        lmax = fmaxf(lmax, __shfl_xor(lmax, 32));
        if (l == 0) { rB[p][w] = loc; rEm[p][w] = fexp(fmaxf(lmax, 1e-35f)); }
        __syncthreads();                  // B1
        sv0 = *(const f32x4*)rB[p];
        sv1 = *(const f32x4*)(rB[p] + 4);
        S = (sv0[0] + sv0[1]) + (sv0[2] + sv0[3])
          + (sv1[0] + sv1[1]) + (sv1[2] + sv1[3]);
        S = fmaxf(S, 1e-35f);
        sc = __builtin_amdgcn_rcpf(S) * 16.f;
        if ((l & 15) == 0) {
#pragma unroll
            for (int ti = 0; ti < 4; ++ti) {
                int d = 0;
                d = __builtin_amdgcn_cvt_pk_fp8_f32(e4[ti][0] * sc, e4[ti][1] * sc, d, false);
                d = __builtin_amdgcn_cvt_pk_fp8_f32(e4[ti][2] * sc, e4[ti][3] * sc, d, true);
                *(u32*)&us8[p][ubase[ti]] = (u32)d;
            }
        }
        __syncthreads();                  // B2
        float lSn = __logf(S);
        if (tid == 0) out[(size_t)b * MM + t] = K + lSn;
        K += C_M + lSn;
        int x = rEm[p][0];
#pragma unroll
        for (int j = 1; j < 8; ++j) x = max(x, rEm[p][j]);
        W = x;                            // after t=2: W = x_2
    }

    // ---- main scan t >= 3: ONE barrier per step, exact 2^(6-W) stale scale ----
#pragma unroll 1
    for (int t = 3; t < MM; ++t) {
        int p = t & 1, pr = p ^ 1;
        const unsigned char* ub = us8[pr];
        f32x4 a0 = {0.f,0.f,0.f,0.f}, a1 = {0.f,0.f,0.f,0.f};
        f32x4 a2 = {0.f,0.f,0.f,0.f}, a3 = {0.f,0.f,0.f,0.f};
        f32x4 b0 = {0.f,0.f,0.f,0.f}, b1 = {0.f,0.f,0.f,0.f};
        f32x4 b2 = {0.f,0.f,0.f,0.f}, b3 = {0.f,0.f,0.f,0.f};
        __builtin_amdgcn_s_setprio(1);
#pragma unroll
        for (int kc = 0; kc < 2; ++kc) {
            i32x8 bbA = *(const i32x8*)(ub + kc * 128 + h32);
            i32x8 bbB = *(const i32x8*)(ub + (kc + 2) * 128 + h32);
            a0 = __builtin_amdgcn_mfma_scale_f32_16x16x128_f8f6f4(pa[0*4+kc],   bbA, a0, 0,0,0, SCL1, 0, SCL1);
            a1 = __builtin_amdgcn_mfma_scale_f32_16x16x128_f8f6f4(pa[1*4+kc],   bbA, a1, 0,0,0, SCL1, 0, SCL1);
            a2 = __builtin_amdgcn_mfma_scale_f32_16x16x128_f8f6f4(pa[2*4+kc],   bbA, a2, 0,0,0, SCL1, 0, SCL1);
            a3 = __builtin_amdgcn_mfma_scale_f32_16x16x128_f8f6f4(pa[3*4+kc],   bbA, a3, 0,0,0, SCL1, 0, SCL1);
            b0 = __builtin_amdgcn_mfma_scale_f32_16x16x128_f8f6f4(pa[0*4+kc+2], bbB, b0, 0,0,0, SCL1, 0, SCL1);
            b1 = __builtin_amdgcn_mfma_scale_f32_16x16x128_f8f6f4(pa[1*4+kc+2], bbB, b1, 0,0,0, SCL1, 0, SCL1);
            b2 = __builtin_amdgcn_mfma_scale_f32_16x16x128_f8f6f4(pa[2*4+kc+2], bbB, b2, 0,0,0, SCL1, 0, SCL1);
            b3 = __builtin_amdgcn_mfma_scale_f32_16x16x128_f8f6f4(pa[3*4+kc+2], bbB, b3, 0,0,0, SCL1, 0, SCL1);
        }
        __builtin_amdgcn_s_setprio(0);
        f32x4 sacc[4] = { a0 + b0, a1 + b1, a2 + b2, a3 + b3 };

        // e = ex * s_raw; local sum + local max
        loc = 0.f;
        float lmax = 0.f;
#pragma unroll
        for (int ti = 0; ti < 4; ++ti)
#pragma unroll
            for (int r = 0; r < 4; ++r) {
                float e = exn[ti][r] * sacc[ti][r];
                e4[ti][r] = e; loc += e;
                lmax = fmaxf(lmax, e);
            }

        // quantize + publish with exact power-of-2 stale scale (PRE-barrier)
        float scf = __int_as_float((133 - W) << 23);   // 2^(6-W)
        if ((l & 15) == 0) {
#pragma unroll
            for (int ti = 0; ti < 4; ++ti) {
                float q0 = fminf(e4[ti][0] * scf, 448.f);
                float q1 = fminf(e4[ti][1] * scf, 448.f);
                float q2 = fminf(e4[ti][2] * scf, 448.f);
                float q3 = fminf(e4[ti][3] * scf, 448.f);
                int d = 0;
                d = __builtin_amdgcn_cvt_pk_fp8_f32(q0, q1, d, false);
                d = __builtin_amdgcn_cvt_pk_fp8_f32(q2, q3, d, true);
                *(u32*)&us8[p][ubase[ti]] = (u32)d;
            }
        }

        // prefetch next emission row (in flight across the barrier — r14-proven)
        int on = obs_s[(t + 1 < MM) ? t + 1 : t];
#pragma unroll
        for (int ti = 0; ti < 4; ++ti)
            exn[ti] = *(const f32x4*)(EX + (size_t)on * NN + (w * 4 + ti) * 16 + r4);

        loc += __shfl_xor(loc, 16);
        loc += __shfl_xor(loc, 32);
        lmax = fmaxf(lmax, __shfl_xor(lmax, 16));
        lmax = fmaxf(lmax, __shfl_xor(lmax, 32));
        if (l == 0) { rB[p][w] = loc; rEm[p][w] = fexp(fmaxf(lmax, 1e-35f)); }
        __syncthreads();                  // the ONLY barrier per step

        // post-barrier: out + W update (off critical path, overlaps next MFMA)
        sv0 = *(const f32x4*)rB[p];
        sv1 = *(const f32x4*)(rB[p] + 4);
        S = (sv0[0] + sv0[1]) + (sv0[2] + sv0[3])
          + (sv1[0] + sv1[1]) + (sv1[2] + sv1[3]);
        S = fmaxf(S, 1e-35f);
        float lSn = __logf(S);
        if (tid == 0) out[(size_t)b * MM + t] = K + lSn;
        K += C_M + LOG16F + (float)(W - 6) * LN2F;   // exact: scale used was 2^(6-W)
        int x = rEm[p][0];
#pragma unroll
        for (int j = 1; j < 8; ++j) x = max(x, rEm[p][j]);
        W = W + ((x - W) >> 1);           // damped exponent tracking
        W = min(110, max(-110, W));
    }
}

extern "C" void kernel_launch(void* const* d_in, const int* in_sizes, int n_in,
                              void* d_out, int out_size, void* d_ws, size_t ws_size,
                              hipStream_t stream) {
    const int*   obs = (const int*)d_in[0];
    const float* pri = (const float*)d_in[1];
    const float* T   = (const float*)d_in[2];
    const float* E   = (const float*)d_in[3];
    float* out = (float*)d_out;
    char* ws = (char*)d_ws;

    float* c   = (float*)(ws + 0);
    float* lp2 = (float*)(ws + 2048);
    float* M   = (float*)(ws + 4096);
    u32*   PA  = (u32*)(ws + 8192);                       // 256 KB fp8 A-frags
    float* EX  = (float*)(ws + 8192 + 256 * 1024);        // 512 KB

    k_col_lse<<<512, 64, 0, stream>>>(T, c);
    k_rowM   <<<512, 64, 0, stream>>>(T, c, M);
    k_prep   <<<641, 64, 0, stream>>>(T, c, M, pri, E, lp2, PA, EX);
    k_scan   <<<BB, 512, 0, stream>>>(obs, lp2, M, PA, EX, out);
}

// Round 17
// 330.419 us; speedup vs baseline: 1.0424x; 1.0001x over previous
//
#include <hip/hip_runtime.h>
#include <hip/hip_bf16.h>
#include <math.h>

#define NN 512   // hidden states
#define MM 256   // timesteps / emission symbols
#define BB 128   // batch

typedef float        f32x4 __attribute__((ext_vector_type(4)));
typedef unsigned int u32;
typedef u32          u32x2 __attribute__((ext_vector_type(2)));
typedef unsigned long long u64;
typedef int          i32x8 __attribute__((ext_vector_type(8)));

#define LOG16F 2.772588722239781f
#define SCL1   0x7F   // E8M0 scale byte = 1.0

__device__ __forceinline__ float wave_max(float v) {
#pragma unroll
    for (int o = 32; o > 0; o >>= 1) v = fmaxf(v, __shfl_xor(v, o));
    return v;
}
__device__ __forceinline__ float wave_sum(float v) {
#pragma unroll
    for (int o = 32; o > 0; o >>= 1) v += __shfl_xor(v, o);
    return v;
}

// ---------------- preprocessing (3 kernels, unchanged from r14) ----------------

__global__ void k_col_lse(const float* __restrict__ T, float* __restrict__ c) {
    int k = blockIdx.x, j = threadIdx.x;
    float m = -INFINITY, s = 0.f;
#pragma unroll
    for (int q = 0; q < 8; ++q) {
        float x = T[(q * 64 + j) * NN + k];
        if (x > m) { s = s * __expf(m - x) + 1.f; m = x; }
        else       { s += __expf(x - m); }
    }
    float mw = wave_max(m);
    float sw = wave_sum(s * __expf(m - mw));
    if (j == 0) c[k] = mw + __logf(sw);
}

__global__ void k_rowM(const float* __restrict__ T, const float* __restrict__ c,
                       float* __restrict__ M) {
    int i = blockIdx.x, j = threadIdx.x;
    float mx = -INFINITY;
#pragma unroll
    for (int d = 0; d < 8; ++d) {
        int k = j * 8 + d;
        mx = fmaxf(mx, T[i * NN + k] - c[k]);
    }
    mx = wave_max(mx);
    if (j == 0) M[i] = mx - __logf(64.f);
}

__global__ void k_prep(const float* __restrict__ T, const float* __restrict__ c,
                       const float* __restrict__ M, const float* __restrict__ pr,
                       const float* __restrict__ E,
                       float* __restrict__ lp2, u32* __restrict__ PA,
                       float* __restrict__ EX) {
    int blk = blockIdx.x, l = threadIdx.x;
    if (blk < 512) {
        float mm = -INFINITY;
#pragma unroll
        for (int q = 0; q < 8; ++q) mm = fmaxf(mm, M[q * 64 + l]);
        float CMv = wave_max(mm);
        int i = blk;
        float v[4];
        float mx = -INFINITY;
#pragma unroll
        for (int d = 0; d < 4; ++d) {
            v[d] = E[i * MM + l * 4 + d];
            mx = fmaxf(mx, v[d]);
        }
        mx = wave_max(mx);
        float s = 0.f;
#pragma unroll
        for (int d = 0; d < 4; ++d) s += __expf(v[d] - mx);
        s = wave_sum(s);
        float lse = mx + __logf(s);
        float add = M[i] - CMv - LOG16F - lse;
#pragma unroll
        for (int d = 0; d < 4; ++d)
            EX[(size_t)(l * 4 + d) * NN + i] = __expf(v[d] + add);
    } else if (blk < 640) {
        int bb = blk - 512;
        int tile = bb >> 2, kc = bb & 3;
        int row = tile * 16 + (l & 15);
        int kb  = kc * 128 + (l >> 4) * 32;
        float Mi = M[row];                // = rowmax - log64
        i32x8 dd;
#pragma unroll
        for (int q = 0; q < 8; ++q) {
            float p0 = __expf(T[row * NN + kb + 4*q + 0] - c[kb + 4*q + 0] - Mi);
            float p1 = __expf(T[row * NN + kb + 4*q + 1] - c[kb + 4*q + 1] - Mi);
            float p2 = __expf(T[row * NN + kb + 4*q + 2] - c[kb + 4*q + 2] - Mi);
            float p3 = __expf(T[row * NN + kb + 4*q + 3] - c[kb + 4*q + 3] - Mi);
            int d = 0;
            d = __builtin_amdgcn_cvt_pk_fp8_f32(p0, p1, d, false);
            d = __builtin_amdgcn_cvt_pk_fp8_f32(p2, p3, d, true);
            dd[q] = d;
        }
        *(i32x8*)(PA + ((size_t)bb * 64 + l) * 8) = dd;
    } else {
        float mm = -INFINITY;
#pragma unroll
        for (int q = 0; q < 8; ++q) mm = fmaxf(mm, M[q * 64 + l]);
        float CMv = wave_max(mm);
        float x[8];
        float mx = -INFINITY;
#pragma unroll
        for (int q = 0; q < 8; ++q) {
            x[q] = pr[q * 64 + l];
            mx = fmaxf(mx, x[q]);
        }
        mx = wave_max(mx);
        float s = 0.f;
#pragma unroll
        for (int q = 0; q < 8; ++q) s += __expf(x[q] - mx);
        s = wave_sum(s);
        float lse = mx + __logf(s);
#pragma unroll
        for (int q = 0; q < 8; ++q) {
            int i = q * 64 + l;
            lp2[i] = __expf(x[q] - lse - M[i] + CMv + LOG16F);
        }
    }
}

// ---------------- the scan (MX K=128, 16 waves / 4 per SIMD) ----------------
// One block per batch, 1024 threads = 16 waves (4 waves/SIMD: doubled
// latency hiding vs the 8-wave version). Wave w owns i-tiles 2w, 2w+1.
// A-frags: 8 x i32x8 = 64 AGPR/lane. r14-proven numerics: fresh scale
// 16/S_t, 2 barriers/step, EX prefetched one step ahead, log/out deferred.
__global__ __launch_bounds__(1024, 1) void k_scan(
        const int* __restrict__ obs, const float* __restrict__ lp2,
        const float* __restrict__ Mrow, const u32* __restrict__ PAu,
        const float* __restrict__ EX, float* __restrict__ out) {
    int b = blockIdx.x, tid = threadIdx.x;
    int w = tid >> 6, l = tid & 63;
    int h32 = (l >> 4) * 32;              // byte offset of this lane's B slice
    int r4 = (l >> 4) * 4;                // row group within a 16-row tile
    __shared__ unsigned char us8[NN] __attribute__((aligned(64)));
    __shared__ float rB[16] __attribute__((aligned(16)));
    __shared__ int obs_s[MM];
    if (tid < MM) obs_s[tid] = obs[b * MM + tid];

    // C_M (8 loads + wave reduce)
    float mm = -INFINITY;
#pragma unroll
    for (int q = 0; q < 8; ++q) mm = fmaxf(mm, Mrow[q * 64 + l]);
    float C_M = wave_max(mm);

    // --- stage A-fragments: 8 x i32x8 per lane (2 tiles x 4 k-chunks) ---
    i32x8 pa[8];
#pragma unroll
    for (int ti = 0; ti < 2; ++ti)
#pragma unroll
        for (int kc = 0; kc < 4; ++kc)
            pa[ti * 4 + kc] = *(const i32x8*)(PAu
                + ((size_t)(((w * 2 + ti) * 4 + kc) * 64) + l) * 8);
#pragma unroll
    for (int q = 0; q < 8; ++q) asm volatile("" : "+a"(pa[q]));  // AGPR-resident

    int ub0 = (w * 2 + 0) * 16 + r4;      // publish byte addresses
    int ub1 = (w * 2 + 1) * 16 + r4;
    __syncthreads();                      // obs_s ready

    // ---- t = 0: e = EX[o0] * lp2 ----
    int o0 = __builtin_amdgcn_readfirstlane(obs_s[0]);
    f32x4 e0, e1;
    float loc = 0.f;
    {
        const float* exr = EX + (size_t)o0 * NN;
        f32x4 xa = *(const f32x4*)(exr + (w * 2 + 0) * 16 + r4);
        f32x4 xb = *(const f32x4*)(exr + (w * 2 + 1) * 16 + r4);
        f32x4 pa0 = *(const f32x4*)(lp2 + (w * 2 + 0) * 16 + r4);
        f32x4 pb0 = *(const f32x4*)(lp2 + (w * 2 + 1) * 16 + r4);
        e0 = xa * pa0; e1 = xb * pb0;
#pragma unroll
        for (int r = 0; r < 4; ++r) loc += e0[r] + e1[r];
    }
    loc += __shfl_xor(loc, 16);
    loc += __shfl_xor(loc, 32);
    if (l == 0) rB[w] = loc;
    __syncthreads();                      // B1
    f32x4 sv0 = *(const f32x4*)rB;
    f32x4 sv1 = *(const f32x4*)(rB + 4);
    f32x4 sv2 = *(const f32x4*)(rB + 8);
    f32x4 sv3 = *(const f32x4*)(rB + 12);
    f32x4 svs = (sv0 + sv1) + (sv2 + sv3);
    float S = (svs[0] + svs[1]) + (svs[2] + svs[3]);
    S = fmaxf(S, 1e-35f);
    float sc = __builtin_amdgcn_rcpf(S) * 16.f;
    if ((l & 15) == 0) {
        int d0 = 0, d1 = 0;
        d0 = __builtin_amdgcn_cvt_pk_fp8_f32(e0[0] * sc, e0[1] * sc, d0, false);
        d0 = __builtin_amdgcn_cvt_pk_fp8_f32(e0[2] * sc, e0[3] * sc, d0, true);
        d1 = __builtin_amdgcn_cvt_pk_fp8_f32(e1[0] * sc, e1[1] * sc, d1, false);
        d1 = __builtin_amdgcn_cvt_pk_fp8_f32(e1[2] * sc, e1[3] * sc, d1, true);
        *(u32*)&us8[ub0] = (u32)d0;
        *(u32*)&us8[ub1] = (u32)d1;
    }
    __syncthreads();                      // B2: us8 ready
    float lS = __logf(S);
    if (tid == 0) out[(size_t)b * MM + 0] = lS;
    float K = C_M + lS;                   // Omega_1

    // prefetch t=1 emission row
    f32x4 xn0, xn1;
    {
        int on = __builtin_amdgcn_readfirstlane(obs_s[1]);
        const float* exr = EX + (size_t)on * NN;
        xn0 = *(const f32x4*)(exr + (w * 2 + 0) * 16 + r4);
        xn1 = *(const f32x4*)(exr + (w * 2 + 1) * 16 + r4);
    }

    // ---- main scan t >= 1 ----
#pragma unroll 1
    for (int t = 1; t < MM; ++t) {
        const unsigned char* ub = us8;
        f32x4 a0 = {0.f,0.f,0.f,0.f}, a1 = {0.f,0.f,0.f,0.f};
        f32x4 b0 = {0.f,0.f,0.f,0.f}, b1 = {0.f,0.f,0.f,0.f};
        __builtin_amdgcn_s_setprio(1);
#pragma unroll
        for (int kc = 0; kc < 2; ++kc) {   // 4 chains of depth 2, 8 MFMA total
            i32x8 bbA = *(const i32x8*)(ub + kc * 128 + h32);
            i32x8 bbB = *(const i32x8*)(ub + (kc + 2) * 128 + h32);
            a0 = __builtin_amdgcn_mfma_scale_f32_16x16x128_f8f6f4(
                     pa[0 * 4 + kc], bbA, a0, 0, 0, 0, SCL1, 0, SCL1);
            a1 = __builtin_amdgcn_mfma_scale_f32_16x16x128_f8f6f4(
                     pa[1 * 4 + kc], bbA, a1, 0, 0, 0, SCL1, 0, SCL1);
            b0 = __builtin_amdgcn_mfma_scale_f32_16x16x128_f8f6f4(
                     pa[0 * 4 + kc + 2], bbB, b0, 0, 0, 0, SCL1, 0, SCL1);
            b1 = __builtin_amdgcn_mfma_scale_f32_16x16x128_f8f6f4(
                     pa[1 * 4 + kc + 2], bbB, b1, 0, 0, 0, SCL1, 0, SCL1);
        }
        __builtin_amdgcn_s_setprio(0);
        f32x4 s0 = a0 + b0, s1 = a1 + b1;

        // e = ex * s_raw (ex prefetched last step)
        e0 = xn0 * s0; e1 = xn1 * s1;
        loc = 0.f;
#pragma unroll
        for (int r = 0; r < 4; ++r) loc += e0[r] + e1[r];

        // prefetch t+1 emission row (in flight across barriers — r14-proven)
        {
            int on = __builtin_amdgcn_readfirstlane(
                         obs_s[(t + 1 < MM) ? t + 1 : t]);
            const float* exr = EX + (size_t)on * NN;
            xn0 = *(const f32x4*)(exr + (w * 2 + 0) * 16 + r4);
            xn1 = *(const f32x4*)(exr + (w * 2 + 1) * 16 + r4);
        }

        loc += __shfl_xor(loc, 16);
        loc += __shfl_xor(loc, 32);
        if (l == 0) rB[w] = loc;
        __syncthreads();                  // B1: rB ready (us8 reads done too)
        sv0 = *(const f32x4*)rB;
        sv1 = *(const f32x4*)(rB + 4);
        sv2 = *(const f32x4*)(rB + 8);
        sv3 = *(const f32x4*)(rB + 12);
        svs = (sv0 + sv1) + (sv2 + sv3);
        S = (svs[0] + svs[1]) + (svs[2] + svs[3]);
        S = fmaxf(S, 1e-35f);
        sc = __builtin_amdgcn_rcpf(S) * 16.f;
        if ((l & 15) == 0) {
            int d0 = 0, d1 = 0;
            d0 = __builtin_amdgcn_cvt_pk_fp8_f32(e0[0] * sc, e0[1] * sc, d0, false);
            d0 = __builtin_amdgcn_cvt_pk_fp8_f32(e0[2] * sc, e0[3] * sc, d0, true);
            d1 = __builtin_amdgcn_cvt_pk_fp8_f32(e1[0] * sc, e1[1] * sc, d1, false);
            d1 = __builtin_amdgcn_cvt_pk_fp8_f32(e1[2] * sc, e1[3] * sc, d1, true);
            *(u32*)&us8[ub0] = (u32)d0;
            *(u32*)&us8[ub1] = (u32)d1;
        }
        __syncthreads();                  // B2: us8 ready for next step
        // deferred bookkeeping (overlaps next step's MFMA)
        float lSn = __logf(S);
        if (tid == 0) out[(size_t)b * MM + t] = K + lSn;
        K += C_M + lSn;                   // Omega_{t+1}
    }
}

extern "C" void kernel_launch(void* const* d_in, const int* in_sizes, int n_in,
                              void* d_out, int out_size, void* d_ws, size_t ws_size,
                              hipStream_t stream) {
    const int*   obs = (const int*)d_in[0];
    const float* pri = (const float*)d_in[1];
    const float* T   = (const float*)d_in[2];
    const float* E   = (const float*)d_in[3];
    float* out = (float*)d_out;
    char* ws = (char*)d_ws;

    float* c   = (float*)(ws + 0);
    float* lp2 = (float*)(ws + 2048);
    float* M   = (float*)(ws + 4096);
    u32*   PA  = (u32*)(ws + 8192);                       // 256 KB fp8 A-frags
    float* EX  = (float*)(ws + 8192 + 256 * 1024);        // 512 KB

    k_col_lse<<<512, 64, 0, stream>>>(T, c);
    k_rowM   <<<512, 64, 0, stream>>>(T, c, M);
    k_prep   <<<641, 64, 0, stream>>>(T, c, M, pri, E, lp2, PA, EX);
    k_scan   <<<BB, 1024, 0, stream>>>(obs, lp2, M, PA, EX, out);
}